// Round 1
// baseline (1185.266 us; speedup 1.0000x reference)
//
#include <hip/hip_runtime.h>

// Problem dims (fixed by setup_inputs): x:(8,64,512,512) f32, flow:(8,2,512,512) f32
#define BB 8
#define CC 64
#define HH 512
#define WW 512
// H*W = 2^18, W = 2^9 -> shift/mask indexing

__global__ __launch_bounds__(256) void align2d_warp_kernel(
    const float* __restrict__ x,
    const float* __restrict__ flow,
    float* __restrict__ out)
{
    const int tid = blockIdx.x * blockDim.x + threadIdx.x;  // b*H*W + h*W + w
    const int w = tid & (WW - 1);
    const int h = (tid >> 9) & (HH - 1);
    const int b = tid >> 18;

    // flow layout: (B, 2, H, W)
    const int pix = h * WW + w;
    const float fx = flow[((size_t)b * 2 + 0) * (HH * WW) + pix];
    const float fy = flow[((size_t)b * 2 + 1) * (HH * WW) + pix];

    // border-clamped bilinear coords (exactly mirrors reference semantics)
    float px = fminf(fmaxf((float)w + fx, 0.0f), (float)(WW - 1));
    float py = fminf(fmaxf((float)h + fy, 0.0f), (float)(HH - 1));
    float x0f = floorf(px);
    float y0f = floorf(py);
    float wx = px - x0f;
    float wy = py - y0f;
    int x0 = (int)x0f;                 // in [0, W-1] after clamp
    int y0 = (int)y0f;
    int x1 = min(x0 + 1, WW - 1);
    int y1 = min(y0 + 1, HH - 1);

    const int o00 = y0 * WW + x0;
    const int o01 = y0 * WW + x1;
    const int o10 = y1 * WW + x0;
    const int o11 = y1 * WW + x1;

    // lerp weights; reference does top/bot lerps — algebraically identical,
    // fp32 compute so rounding diff is ~1e-7, threshold is 1e-1.
    const float w00 = (1.0f - wx) * (1.0f - wy);
    const float w01 = wx * (1.0f - wy);
    const float w10 = (1.0f - wx) * wy;
    const float w11 = wx * wy;

    const float* xb = x   + (size_t)b * CC * HH * WW;
    float*       ob = out + (size_t)b * CC * HH * WW;

    #pragma unroll 4
    for (int c = 0; c < CC; ++c) {
        const float* p = xb + c * (HH * WW);
        float v = p[o00] * w00 + p[o01] * w01 + p[o10] * w10 + p[o11] * w11;
        ob[c * (HH * WW) + pix] = v;
    }
}

// pass-through copy of flow into the tail of d_out (16 MiB, float4)
__global__ __launch_bounds__(256) void align2d_flowcopy_kernel(
    const float4* __restrict__ flow, float4* __restrict__ out)
{
    const int i = blockIdx.x * blockDim.x + threadIdx.x;
    out[i] = flow[i];
}

extern "C" void kernel_launch(void* const* d_in, const int* in_sizes, int n_in,
                              void* d_out, int out_size, void* d_ws, size_t ws_size,
                              hipStream_t stream) {
    const float* x    = (const float*)d_in[0];
    const float* flow = (const float*)d_in[1];
    float* out = (float*)d_out;

    const int npix = BB * HH * WW;                 // 2,097,152
    align2d_warp_kernel<<<npix / 256, 256, 0, stream>>>(x, flow, out);

    const int nflow4 = (BB * 2 * HH * WW) / 4;     // 1,048,576 float4
    float* out_flow = out + (size_t)BB * CC * HH * WW;
    align2d_flowcopy_kernel<<<nflow4 / 256, 256, 0, stream>>>(
        (const float4*)flow, (float4*)out_flow);
}